// Round 2
// baseline (83.915 us; speedup 1.0000x reference)
//
#include <hip/hip_runtime.h>
#include <math.h>

#define NPTS   4096
#define NB     8
#define IR     4                          // i-points per thread
#define TILE   (64 * IR)                  // 256 i-points per block
#define NTILE  (NPTS / TILE)              // 16
#define NWAVES 16
#define BLK    (NWAVES * 64)              // 1024 threads
#define NHALF  2                          // j-range split across 2 blocks per tile
#define JHALF  (NPTS / NHALF)             // 2048
#define JCHUNK (JHALF / NWAVES)           // 128 j per wave
#define INV_H2 (1.0f / (0.03f * 0.03f))
#define INFV   3.0e38f

__device__ __forceinline__ float med3f(float a, float b, float c) {
#if defined(__has_builtin)
#if __has_builtin(__builtin_amdgcn_fmed3f)
  return __builtin_amdgcn_fmed3f(a, b, c);
#else
  return fminf(c, fmaxf(a, b));
#endif
#else
  return fminf(c, fmaxf(a, b));
#endif
}

// Scan LDS points [lo,hi) for FOUR i-points per thread, in sq_i-folded space:
// t = sq_j - 2*p_i.p_j  (top-4 selection invariant under +sq_i; applied in finalize).
// 3 FMA + 4-op sorted insert per (i,j). CHECK compares j against all 4 self indices.
template <bool CHECK>
__device__ __forceinline__ void scan4(const float4* __restrict__ sP, int lo, int hi,
                                      const int self[IR],
                                      const float mx[IR], const float my[IR],
                                      const float mz[IR], float t[IR][4]) {
#pragma unroll 4
  for (int j = lo; j < hi; ++j) {
    float4 q = sP[j];                     // ds_read_b128, wave-uniform addr (broadcast)
#pragma unroll
    for (int k = 0; k < IR; ++k) {
      float d = fmaf(mx[k], q.x, fmaf(my[k], q.y, fmaf(mz[k], q.z, q.w)));
      if (CHECK) d = (j == self[k]) ? INFV : d;
      t[k][3] = med3f(t[k][2], d, t[k][3]);
      t[k][2] = med3f(t[k][1], d, t[k][2]);
      t[k][1] = med3f(t[k][0], d, t[k][1]);
      t[k][0] = fminf(t[k][0], d);
    }
  }
}

// lowest-4 (ascending) of two ascending 4-lists. Safe when outputs alias inputs.
__device__ __forceinline__ void merge4(float a0, float a1, float a2, float a3,
                                       float b0, float b1, float b2, float b3,
                                       float& o0, float& o1, float& o2, float& o3) {
  float L0 = fminf(a0, b3), L1 = fminf(a1, b2), L2 = fminf(a2, b1), L3 = fminf(a3, b0);
  float e0 = fminf(L0, L2), e2 = fmaxf(L0, L2);
  float e1 = fminf(L1, L3), e3 = fmaxf(L1, L3);
  o0 = fminf(e0, e1); o1 = fmaxf(e0, e1);
  o2 = fminf(e2, e3); o3 = fmaxf(e2, e3);
}

// Kernel 1: each block handles one (batch, tile, j-half). Writes per-i partial
// 4-lists (t-space) to workspace: ws[((b*NTILE+tile)*NHALF+h)*TILE + i].
__global__ __launch_bounds__(BLK)
void repulsion_scan(const float* __restrict__ pc, float4* __restrict__ ws) {
  __shared__ float4 sP[NPTS];                  // 64 KB: x,y,z,||p||^2
  __shared__ float4 cand[NWAVES * TILE];       // 64 KB: per-wave partial 4-lists

  const int blk  = blockIdx.x;
  const int b    = blk >> 5;                   // / (NTILE*NHALF) = /32
  const int r    = blk & 31;
  const int tile = r >> 1;
  const int h    = r & 1;
  const int tid  = threadIdx.x;
  const float4* pcv = (const float4*)(pc + (size_t)b * NPTS * 3);

  // Stage batch into LDS: each thread loads 3 float4 -> 4 points (1024 groups).
  {
    const int g = tid;                         // BLK == NPTS/4
    float4 a = pcv[3 * g + 0];
    float4 c = pcv[3 * g + 1];
    float4 e = pcv[3 * g + 2];
    float x0 = a.x, y0 = a.y, z0 = a.z;
    float x1 = a.w, y1 = c.x, z1 = c.y;
    float x2 = c.z, y2 = c.w, z2 = e.x;
    float x3 = e.y, y3 = e.z, z3 = e.w;
    sP[4 * g + 0] = make_float4(x0, y0, z0, fmaf(x0, x0, fmaf(y0, y0, z0 * z0)));
    sP[4 * g + 1] = make_float4(x1, y1, z1, fmaf(x1, x1, fmaf(y1, y1, z1 * z1)));
    sP[4 * g + 2] = make_float4(x2, y2, z2, fmaf(x2, x2, fmaf(y2, y2, z2 * z2)));
    sP[4 * g + 3] = make_float4(x3, y3, z3, fmaf(x3, x3, fmaf(y3, y3, z3 * z3)));
  }
  __syncthreads();

  const int w    = tid >> 6;                   // wave index = j-chunk within half
  const int lane = tid & 63;

  int   self[IR];
  float mx[IR], my[IR], mz[IR], t[IR][4];
#pragma unroll
  for (int k = 0; k < IR; ++k) {
    self[k] = tile * TILE + 64 * k + lane;
    float4 p = sP[self[k]];
    mx[k] = -2.0f * p.x; my[k] = -2.0f * p.y; mz[k] = -2.0f * p.z;
    t[k][0] = INFV; t[k][1] = INFV; t[k][2] = INFV; t[k][3] = INFV;
  }

  const int j0 = h * JHALF + w * JCHUNK;
  // This wave's 128-j window intersects the tile's i-range iff the half matches
  // and (w>>1) == (tile&7); for those waves the whole chunk runs with self-check.
  const bool check = (h == (tile >> 3)) && ((w >> 1) == (tile & 7));
  if (check)
    scan4<true >(sP, j0, j0 + JCHUNK, self, mx, my, mz, t);
  else
    scan4<false>(sP, j0, j0 + JCHUNK, self, mx, my, mz, t);

#pragma unroll
  for (int k = 0; k < IR; ++k)
    cand[w * TILE + 64 * k + lane] = make_float4(t[k][0], t[k][1], t[k][2], t[k][3]);
  __syncthreads();

  // Merge 16 per-wave lists per i-point; threads 0..255, one i each.
  if (tid < TILE) {
    float4 M = cand[tid];
    float m0 = M.x, m1 = M.y, m2 = M.z, m3 = M.w;
#pragma unroll
    for (int ww = 1; ww < NWAVES; ++ww) {
      float4 Cw = cand[ww * TILE + tid];
      merge4(m0, m1, m2, m3, Cw.x, Cw.y, Cw.z, Cw.w, m0, m1, m2, m3);
    }
    ws[((size_t)(b * NTILE + tile) * NHALF + h) * TILE + tid] =
        make_float4(m0, m1, m2, m3);
  }
}

// Kernel 2: merge the two j-half lists per i, un-fold sq_i, accumulate loss.
__global__ __launch_bounds__(TILE)
void repulsion_finalize(const float* __restrict__ pc, const float4* __restrict__ ws,
                        float* __restrict__ out) {
  const int blk  = blockIdx.x;                 // NB * NTILE = 128 blocks
  const int b    = blk >> 4;
  const int tile = blk & 15;
  const int tid  = threadIdx.x;                // 256 threads, one i each

  const size_t base = (size_t)(b * NTILE + tile) * NHALF;
  float4 A = ws[(base + 0) * TILE + tid];
  float4 B = ws[(base + 1) * TILE + tid];
  float m0, m1, m2, m3;
  merge4(A.x, A.y, A.z, A.w, B.x, B.y, B.z, B.w, m0, m1, m2, m3);

  const float* p = pc + ((size_t)b * NPTS + tile * TILE + tid) * 3;
  const float px = p[0], py = p[1], pz = p[2];
  const float sqi = fmaf(px, px, fmaf(py, py, pz * pz));

  float d0 = fmaxf(m0 + sqi, 0.0f);
  float d1 = fmaxf(m1 + sqi, 0.0f);
  float d2 = fmaxf(m2 + sqi, 0.0f);
  float d3 = fmaxf(m3 + sqi, 0.0f);

  float s = 0.0f;
  s -= d0 * expf(-d0 * INV_H2);
  s -= d1 * expf(-d1 * INV_H2);
  s -= d2 * expf(-d2 * INV_H2);
  s -= d3 * expf(-d3 * INV_H2);

  for (int off = 32; off > 0; off >>= 1) s += __shfl_down(s, off);

  __shared__ float wsum[TILE / 64];
  if ((tid & 63) == 0) wsum[tid >> 6] = s;
  __syncthreads();
  if (tid == 0) {
    float tot = 0.0f;
#pragma unroll
    for (int i = 0; i < TILE / 64; ++i) tot += wsum[i];
    atomicAdd(out, tot);
  }
}

extern "C" void kernel_launch(void* const* d_in, const int* in_sizes, int n_in,
                              void* d_out, int out_size, void* d_ws, size_t ws_size,
                              hipStream_t stream) {
  const float* pc = (const float*)d_in[0];
  float* out = (float*)d_out;
  float4* ws = (float4*)d_ws;                  // needs 8*16*2*256*16 B = 1 MiB
  hipMemsetAsync(out, 0, sizeof(float), stream);
  repulsion_scan<<<dim3(NB * NTILE * NHALF), dim3(BLK), 0, stream>>>(pc, ws);
  repulsion_finalize<<<dim3(NB * NTILE), dim3(TILE), 0, stream>>>(pc, ws, out);
}